// Round 1
// baseline (1083.077 us; speedup 1.0000x reference)
//
#include <hip/hip_runtime.h>
#include <math.h>

constexpr int D  = 512;
constexpr int T  = 8192;
constexpr int B  = 8;
constexpr int H  = 8;
constexpr int KS = 64;   // slots
constexpr int HD = 64;   // head dim
constexpr float SCALE  = 0.125f;   // 1/sqrt(64)
constexpr float LNEPS  = 1e-5f;
constexpr float EPS    = 1e-20f;

constexpr int TC = 128;  // tokens per block
constexpr int BK = 32;

// workspace offsets (floats)
constexpr size_t OFF_S    = 0;                      // 64*512
constexpr size_t OFF_WBIG = 32768;                  // 512*1024: cols 0..511 = Weff, 512..1023 = Wv^T
constexpr size_t OFF_BQ   = OFF_WBIG + 512*1024;    // 512
constexpr size_t OFF_SACC = OFF_BQ + 512;           // B*H*64*64
constexpr size_t OFF_CACC = OFF_SACC + (size_t)B*H*KS*HD;  // B*H*64

// ---------- setup: layernorm of slots ----------
__global__ void ln_slots_kernel(const float* __restrict__ slots_w,
                                const float* __restrict__ g, const float* __restrict__ b,
                                float* __restrict__ S) {
  __shared__ float red[8];
  int k = blockIdx.x;
  int tid = threadIdx.x;
  float x0 = slots_w[k*D + tid];
  float x1 = slots_w[k*D + tid + 256];
  float s1 = x0 + x1, s2 = x0*x0 + x1*x1;
  for (int off = 32; off; off >>= 1) { s1 += __shfl_xor(s1, off); s2 += __shfl_xor(s2, off); }
  if ((tid & 63) == 0) { red[tid >> 6] = s1; red[4 + (tid >> 6)] = s2; }
  __syncthreads();
  s1 = red[0] + red[1] + red[2] + red[3];
  s2 = red[4] + red[5] + red[6] + red[7];
  float mu = s1 / D;
  float var = s2 / D - mu * mu;
  float rs = rsqrtf(var + LNEPS);
  S[k*D + tid]       = (x0 - mu) * rs * g[tid]       + b[tid];
  S[k*D + tid + 256] = (x1 - mu) * rs * g[tid + 256] + b[tid + 256];
}

// ---------- setup: Weff[in][hk] = scale * sum_d S[k][h*64+d] * Wk[h*64+d][in] ----------
__global__ void weff_kernel(const float* __restrict__ S, const float* __restrict__ Wk,
                            float* __restrict__ Wbig) {
  int gid = blockIdx.x * 256 + threadIdx.x;   // 0..262143
  int in = gid & 511;
  int hk = gid >> 9;          // uniform per block
  int h = hk >> 6, k = hk & 63;
  const float* srow = S + k*D + h*HD;
  const float* wcol = Wk + (size_t)(h*HD)*D + in;
  float acc = 0.f;
  #pragma unroll 8
  for (int d = 0; d < HD; ++d) acc += srow[d] * wcol[(size_t)d*D];
  Wbig[(size_t)in*1024 + hk] = acc * SCALE;
}

// ---------- setup: bq[hk] = scale * sum_d S[k][h*64+d] * bk[h*64+d] ----------
__global__ void bq_kernel(const float* __restrict__ S, const float* __restrict__ bk,
                          float* __restrict__ bq) {
  int hk = blockIdx.x * 256 + threadIdx.x;
  int h = hk >> 6, k = hk & 63;
  float acc = 0.f;
  for (int d = 0; d < HD; ++d) acc += S[k*D + h*HD + d] * bk[h*HD + d];
  bq[hk] = acc * SCALE;
}

// ---------- setup: Wbig[in][512+out] = Wv[out][in] (transpose) ----------
__global__ void wvt_kernel(const float* __restrict__ Wv, float* __restrict__ Wbig) {
  __shared__ float t[32][33];
  int bx = blockIdx.x * 32;  // in base
  int by = blockIdx.y * 32;  // out base
  int x = threadIdx.x, y0 = threadIdx.y;  // block (32,8)
  #pragma unroll
  for (int m = 0; m < 4; ++m) {
    int y = y0 + m*8;
    t[y][x] = Wv[(size_t)(by + y)*D + bx + x];
  }
  __syncthreads();
  #pragma unroll
  for (int m = 0; m < 4; ++m) {
    int y = y0 + m*8;
    Wbig[(size_t)(bx + y)*1024 + 512 + by + x] = t[x][y];
  }
}

__global__ void zero_kernel(float* __restrict__ p, int n) {
  int gid = blockIdx.x * 256 + threadIdx.x;
  if (gid < n) p[gid] = 0.f;
}

// ---------- main fused kernel: per (chunk, head, batch) ----------
// Phase 1: 128x128 tile = [Xchunk(128x512)] @ [Weff_h | WvT_h] (512x128)
// Phase 2: softmax over slot cols (0..63), then S_part(64x64) = W^T @ V, atomic accum.
__global__ __launch_bounds__(256, 2) void main_kernel(
    const float* __restrict__ X, const float* __restrict__ Wbig,
    const float* __restrict__ bq, const float* __restrict__ bv,
    float* __restrict__ Sacc, float* __restrict__ Cacc) {
  __shared__ float smem[16384];             // 64 KB union
  float* Xs  = smem;                        // [BK][132]
  float* Bs  = smem + 4224;                 // [BK][132]
  float* Ws2 = smem;                        // [128][64]
  float* Vt2 = smem + 8192;                 // [128][64]

  int tid = threadIdx.x;
  int tx = tid & 15, ty = tid >> 4;
  int chunk = blockIdx.x, h = blockIdx.y, b = blockIdx.z;
  const float* Xb = X + ((size_t)b*T + (size_t)chunk*TC) * D;

  float acc[8][8] = {};

  for (int kb = 0; kb < D; kb += BK) {
    __syncthreads();
    // stage X tile (128 rows x 32 cols), transposed into Xs[c][row]
    #pragma unroll
    for (int m = 0; m < 4; ++m) {
      int idx = tid + m*256;
      int row = idx >> 3;
      int c4  = (idx & 7) * 4;
      const float4 xv = *reinterpret_cast<const float4*>(Xb + (size_t)row*D + kb + c4);
      Xs[(c4+0)*132 + row] = xv.x;
      Xs[(c4+1)*132 + row] = xv.y;
      Xs[(c4+2)*132 + row] = xv.z;
      Xs[(c4+3)*132 + row] = xv.w;
    }
    // stage B tile (32 rows x 128 cols): cols 0..63 from Weff_h, 64..127 from WvT_h
    #pragma unroll
    for (int m = 0; m < 4; ++m) {
      int idx = tid + m*256;
      int row = idx >> 5;
      int c   = (idx & 31) * 4;
      int gcol = (c < 64) ? (h*HD + c) : (512 + h*HD + (c - 64));
      const float4 wv = *reinterpret_cast<const float4*>(Wbig + (size_t)(kb + row)*1024 + gcol);
      *reinterpret_cast<float4*>(&Bs[row*132 + c]) = wv;
    }
    __syncthreads();
    #pragma unroll
    for (int kk = 0; kk < BK; ++kk) {
      float a[8], bb[8];
      *reinterpret_cast<float4*>(&a[0])  = *reinterpret_cast<const float4*>(&Xs[kk*132 + ty*8]);
      *reinterpret_cast<float4*>(&a[4])  = *reinterpret_cast<const float4*>(&Xs[kk*132 + ty*8 + 4]);
      *reinterpret_cast<float4*>(&bb[0]) = *reinterpret_cast<const float4*>(&Bs[kk*132 + tx*8]);
      *reinterpret_cast<float4*>(&bb[4]) = *reinterpret_cast<const float4*>(&Bs[kk*132 + tx*8 + 4]);
      #pragma unroll
      for (int i = 0; i < 8; ++i)
        #pragma unroll
        for (int j = 0; j < 8; ++j)
          acc[i][j] = fmaf(a[i], bb[j], acc[i][j]);
    }
  }
  __syncthreads();  // done with Xs/Bs; smem is reused below

  // bias + softmax over slot axis (cols 0..63 live in lanes tx<8)
  if (tx < 8) {
    float bqv[8];
    #pragma unroll
    for (int j = 0; j < 8; ++j) bqv[j] = bq[h*HD + tx*8 + j];
    #pragma unroll
    for (int i = 0; i < 8; ++i) {
      float m = -1e30f;
      #pragma unroll
      for (int j = 0; j < 8; ++j) { acc[i][j] += bqv[j]; m = fmaxf(m, acc[i][j]); }
      m = fmaxf(m, __shfl_xor(m, 1));
      m = fmaxf(m, __shfl_xor(m, 2));
      m = fmaxf(m, __shfl_xor(m, 4));
      float s = 0.f;
      #pragma unroll
      for (int j = 0; j < 8; ++j) { acc[i][j] = __expf(acc[i][j] - m); s += acc[i][j]; }
      s += __shfl_xor(s, 1);
      s += __shfl_xor(s, 2);
      s += __shfl_xor(s, 4);
      float inv = 1.f / s;
      #pragma unroll
      for (int j = 0; j < 8; ++j) {
        acc[i][j] *= inv;
        Ws2[(ty*8 + i)*64 + tx*8 + j] = acc[i][j];
      }
    }
  } else {
    float bvv[8];
    #pragma unroll
    for (int j = 0; j < 8; ++j) bvv[j] = bv[h*HD + (tx - 8)*8 + j];
    #pragma unroll
    for (int i = 0; i < 8; ++i)
      #pragma unroll
      for (int j = 0; j < 8; ++j)
        Vt2[(ty*8 + i)*64 + (tx - 8)*8 + j] = acc[i][j] + bvv[j];
  }
  __syncthreads();

  // phase 2: S_part[k][d'] = sum_r Ws2[r][k] * Vt2[r][d']
  float acc2[4][4] = {};
  #pragma unroll 4
  for (int r = 0; r < TC; ++r) {
    float a2[4], b2[4];
    *reinterpret_cast<float4*>(a2) = *reinterpret_cast<const float4*>(&Ws2[r*64 + ty*4]);
    *reinterpret_cast<float4*>(b2) = *reinterpret_cast<const float4*>(&Vt2[r*64 + tx*4]);
    #pragma unroll
    for (int i = 0; i < 4; ++i)
      #pragma unroll
      for (int j = 0; j < 4; ++j)
        acc2[i][j] = fmaf(a2[i], b2[j], acc2[i][j]);
  }
  float* Sbase = Sacc + ((size_t)b*H + h) * KS * HD;
  #pragma unroll
  for (int i = 0; i < 4; ++i)
    #pragma unroll
    for (int j = 0; j < 4; ++j)
      atomicAdd(&Sbase[(ty*4 + i)*HD + tx*4 + j], acc2[i][j]);

  if (tid < KS) {
    float cs = 0.f;
    for (int r = 0; r < TC; ++r) cs += Ws2[r*64 + tid];
    atomicAdd(&Cacc[((size_t)b*H + h)*KS + tid], cs);
  }
}

// ---------- finalize: divide by (C+eps), layernorm, write out ----------
__global__ void finalize_kernel(const float* __restrict__ Sacc, const float* __restrict__ Cacc,
                                const float* __restrict__ g, const float* __restrict__ bb,
                                float* __restrict__ out) {
  __shared__ float red[8];
  int bk_ = blockIdx.x;           // b*64 + k
  int b = bk_ >> 6, k = bk_ & 63;
  int tid = threadIdx.x;
  float v[2];
  #pragma unroll
  for (int m = 0; m < 2; ++m) {
    int d = tid + m*256;
    int h = d >> 6, dd = d & 63;
    float c = Cacc[((size_t)b*H + h)*KS + k];
    v[m] = Sacc[(((size_t)b*H + h)*KS + k)*HD + dd] / (c + EPS);
  }
  float s1 = v[0] + v[1], s2 = v[0]*v[0] + v[1]*v[1];
  for (int off = 32; off; off >>= 1) { s1 += __shfl_xor(s1, off); s2 += __shfl_xor(s2, off); }
  if ((tid & 63) == 0) { red[tid >> 6] = s1; red[4 + (tid >> 6)] = s2; }
  __syncthreads();
  s1 = red[0] + red[1] + red[2] + red[3];
  s2 = red[4] + red[5] + red[6] + red[7];
  float mu = s1 / D;
  float var = s2 / D - mu * mu;
  float rs = rsqrtf(var + LNEPS);
  #pragma unroll
  for (int m = 0; m < 2; ++m) {
    int d = tid + m*256;
    out[(size_t)bk_*D + d] = (v[m] - mu) * rs * g[d] + bb[d];
  }
}

extern "C" void kernel_launch(void* const* d_in, const int* in_sizes, int n_in,
                              void* d_out, int out_size, void* d_ws, size_t ws_size,
                              hipStream_t stream) {
  const float* X       = (const float*)d_in[0];
  const float* slots_w = (const float*)d_in[1];
  const float* g_slots = (const float*)d_in[2];
  const float* b_slots = (const float*)d_in[3];
  const float* Wk      = (const float*)d_in[4];
  const float* bk      = (const float*)d_in[5];
  const float* Wv      = (const float*)d_in[6];
  const float* bv      = (const float*)d_in[7];
  const float* g_after = (const float*)d_in[8];
  const float* b_after = (const float*)d_in[9];
  float* ws   = (float*)d_ws;
  float* S    = ws + OFF_S;
  float* Wbig = ws + OFF_WBIG;
  float* bq   = ws + OFF_BQ;
  float* Sacc = ws + OFF_SACC;
  float* Cacc = ws + OFF_CACC;
  float* out  = (float*)d_out;

  hipLaunchKernelGGL(ln_slots_kernel, dim3(64), dim3(256), 0, stream, slots_w, g_slots, b_slots, S);
  hipLaunchKernelGGL(weff_kernel, dim3(1024), dim3(256), 0, stream, S, Wk, Wbig);
  hipLaunchKernelGGL(bq_kernel, dim3(2), dim3(256), 0, stream, S, bk, bq);
  hipLaunchKernelGGL(wvt_kernel, dim3(16, 16), dim3(32, 8), 0, stream, Wv, Wbig);
  hipLaunchKernelGGL(zero_kernel, dim3((B*H*KS*HD + B*H*KS + 255) / 256), dim3(256), 0, stream,
                     Sacc, B*H*KS*HD + B*H*KS);
  hipLaunchKernelGGL(main_kernel, dim3(T / TC, H, B), dim3(256), 0, stream,
                     X, Wbig, bq, bv, Sacc, Cacc);
  hipLaunchKernelGGL(finalize_kernel, dim3(B * KS), dim3(256), 0, stream,
                     Sacc, Cacc, g_after, b_after, out);
}

// Round 2
// 362.978 us; speedup vs baseline: 2.9839x; 2.9839x over previous
//
#include <hip/hip_runtime.h>
#include <hip/hip_bf16.h>
#include <math.h>

typedef unsigned short ushort_t;
typedef unsigned int u32;

constexpr int D  = 512;
constexpr int T  = 8192;
constexpr int B  = 8;
constexpr int H  = 8;
constexpr int KS = 64;
constexpr int HD = 64;
constexpr float SCALE = 0.125f;
constexpr float LNEPS = 1e-5f;
constexpr float EPS   = 1e-20f;

constexpr int TC  = 128;   // tokens per chunk
constexpr int CPB = 2;     // chunks per block

// ws layout (float units)
constexpr size_t OFF_S    = 0;         // 64*512
constexpr size_t OFF_BQ   = 32768;     // 512
constexpr size_t OFF_SACC = 33280;     // 8*8*64*64 = 262144
constexpr size_t OFF_CACC = 295424;    // 8*8*64 = 4096
constexpr size_t OFF_WB2  = 299520;    // bf16[1024*512] (1 MB) lives here

typedef __attribute__((ext_vector_type(8))) short bf16x8;
typedef __attribute__((ext_vector_type(4))) float f32x4;
typedef __attribute__((ext_vector_type(4))) unsigned short us4;

typedef const __attribute__((address_space(1))) u32* gas_ptr;
typedef __attribute__((address_space(3))) u32* las_ptr;

__device__ __forceinline__ void gload16(const void* g, void* l) {
  __builtin_amdgcn_global_load_lds((gas_ptr)g, (las_ptr)l, 16, 0, 0);
}

__device__ __forceinline__ ushort_t f2bf(float x) {
  __hip_bfloat16 t = __float2bfloat16(x);
  return *(ushort_t*)&t;
}

__device__ __forceinline__ u32 pk2bf(float x, float y) {
  __hip_bfloat162 t = __float22bfloat162_rn(make_float2(x, y));
  return *(u32*)&t;
}

__device__ __forceinline__ bf16x8 cvt8(f32x4 a, f32x4 b) {
  union { bf16x8 v; u32 u[4]; } r;
  r.u[0] = pk2bf(a.x, a.y); r.u[1] = pk2bf(a.z, a.w);
  r.u[2] = pk2bf(b.x, b.y); r.u[3] = pk2bf(b.z, b.w);
  return r.v;
}

// ---------- setup: layernorm of slots ----------
__global__ void ln_slots_kernel(const float* __restrict__ slots_w,
                                const float* __restrict__ g, const float* __restrict__ b,
                                float* __restrict__ S) {
  __shared__ float red[8];
  int k = blockIdx.x;
  int tid = threadIdx.x;
  float x0 = slots_w[k*D + tid];
  float x1 = slots_w[k*D + tid + 256];
  float s1 = x0 + x1, s2 = x0*x0 + x1*x1;
  for (int off = 32; off; off >>= 1) { s1 += __shfl_xor(s1, off); s2 += __shfl_xor(s2, off); }
  if ((tid & 63) == 0) { red[tid >> 6] = s1; red[4 + (tid >> 6)] = s2; }
  __syncthreads();
  s1 = red[0] + red[1] + red[2] + red[3];
  s2 = red[4] + red[5] + red[6] + red[7];
  float mu = s1 / D;
  float var = s2 / D - mu * mu;
  float rs = rsqrtf(var + LNEPS);
  S[k*D + tid]       = (x0 - mu) * rs * g[tid]       + b[tid];
  S[k*D + tid + 256] = (x1 - mu) * rs * g[tid + 256] + b[tid + 256];
}

// ---------- setup: Wb2[(h*128+k)][in] = bf16(scale * sum_d S[k][h*64+d] * Wk[h*64+d][in]) ----------
__global__ void weff_kernel(const float* __restrict__ S, const float* __restrict__ Wk,
                            ushort_t* __restrict__ Wb2) {
  int gid = blockIdx.x * 256 + threadIdx.x;   // 0..262143
  int in = gid & 511;
  int hk = gid >> 9;          // uniform per block
  int h = hk >> 6, k = hk & 63;
  const float* srow = S + k*D + h*HD;
  const float* wcol = Wk + (size_t)(h*HD)*D + in;
  float acc = 0.f;
  #pragma unroll 8
  for (int d = 0; d < HD; ++d) acc += srow[d] * wcol[(size_t)d*D];
  Wb2[(size_t)(h*128 + k)*D + in] = f2bf(acc * SCALE);
}

// ---------- setup: bq[hk] = scale * sum_d S[k][h*64+d] * bk[h*64+d] ----------
__global__ void bq_kernel(const float* __restrict__ S, const float* __restrict__ bk,
                          float* __restrict__ bq) {
  int hk = blockIdx.x * 256 + threadIdx.x;
  int h = hk >> 6, k = hk & 63;
  float acc = 0.f;
  for (int d = 0; d < HD; ++d) acc += S[k*D + h*HD + d] * bk[h*HD + d];
  bq[hk] = acc * SCALE;
}

// ---------- setup: Wb2[(h*128+64+d)][in] = bf16(Wv[h*64+d][in]) ----------
__global__ void wvcopy_kernel(const float* __restrict__ Wv, ushort_t* __restrict__ Wb2) {
  int gid = blockIdx.x * 256 + threadIdx.x;   // 0..262143
  int in = gid & 511;
  int hd = gid >> 9;
  int h = hd >> 6, d = hd & 63;
  Wb2[(size_t)(h*128 + 64 + d)*D + in] = f2bf(Wv[(size_t)hd*D + in]);
}

__global__ void zero_kernel(float* __restrict__ p, int n) {
  int gid = blockIdx.x * 256 + threadIdx.x;
  if (gid < n) p[gid] = 0.f;
}

// ---------- main fused MFMA kernel ----------
// grid = 2048 blocks, 256 threads (4 waves, 2x2 wave grid).
// block -> (chunk-group cg, head h) via XCD-aware swizzle (8 heads of one cg share id%8 -> same XCD L2)
__global__ __launch_bounds__(256, 3) void main_kernel(
    const float* __restrict__ X, const ushort_t* __restrict__ Wb2,
    const float* __restrict__ bq, const float* __restrict__ bv,
    float* __restrict__ Sacc, float* __restrict__ Cacc) {
  __shared__ __align__(16) char smem[34816];
  float*    A_lds = (float*)smem;                     // [128][32] fp32 X tile (16 KB)
  ushort_t* B_lds = (ushort_t*)(smem + 16384);        // [128][32] bf16 weight tile (8 KB)
  ushort_t* W_lds = (ushort_t*)smem;                  // [64 slots][136 tokens] bf16
  ushort_t* V_lds = (ushort_t*)(smem + 17408);        // [64 dims ][136 tokens] bf16

  const int tid  = threadIdx.x;
  const int lane = tid & 63, w = tid >> 6;
  const int wm = w & 1, wn = w >> 1;
  const int m16 = lane & 15, q = lane >> 4;

  const int id = blockIdx.x;
  const int h  = (id >> 3) & 7;
  const int cg = (id & 7) | ((id >> 6) << 3);         // 0..255
  const int bh = (cg >> 5) * H + h;                    // batch*H + head

  f32x4 acc2[4] = {};                                  // phase-2 accum (16 slots x 64 dims per wave)
  float csum[4] = {0.f, 0.f, 0.f, 0.f};

  for (int cc = 0; cc < CPB; ++cc) {
    const float* Xc = X + (size_t)(cg * CPB + cc) * TC * D;
    f32x4 acc[4][4] = {};                              // phase-1 accum 64x64 per wave

    for (int kb = 0; kb < D; kb += 32) {
      __syncthreads();
      // stage X tile: 128 rows x 32 k, fp32, via global_load_lds (lane-contiguous LDS)
      #pragma unroll
      for (int m = 0; m < 4; ++m) {
        int li = tid + m * 256;                        // 0..1023
        int row = li >> 3, c = li & 7;
        gload16(Xc + (size_t)row * D + kb + c * 4, A_lds + (size_t)li * 4);
      }
      // stage weight tile: 128 cols x 32 k, bf16 (col-major source)
      #pragma unroll
      for (int m = 0; m < 2; ++m) {
        int li = tid + m * 256;                        // 0..511
        int col = li >> 2, c = li & 3;
        gload16(Wb2 + (size_t)(h * 128 + col) * D + kb + c * 8, B_lds + (size_t)li * 8);
      }
      __syncthreads();
      bf16x8 af[4], bf[4];
      #pragma unroll
      for (int i = 0; i < 4; ++i) {
        const f32x4* ap = (const f32x4*)(A_lds + (wm * 64 + i * 16 + m16) * 32 + q * 8);
        af[i] = cvt8(ap[0], ap[1]);
      }
      #pragma unroll
      for (int j = 0; j < 4; ++j)
        bf[j] = *(const bf16x8*)(B_lds + (wn * 64 + j * 16 + m16) * 32 + q * 8);
      #pragma unroll
      for (int i = 0; i < 4; ++i)
        #pragma unroll
        for (int j = 0; j < 4; ++j)
          acc[i][j] = __builtin_amdgcn_mfma_f32_16x16x32_bf16(af[i], bf[j], acc[i][j], 0, 0, 0);
    }
    __syncthreads();   // phase-1 LDS reads done; safe to overwrite with W/V

    if (wn == 0) {
      // these waves hold logits: cols (lane&15)+j*16 = slots, rows = tokens
      float bqv[4];
      #pragma unroll
      for (int j = 0; j < 4; ++j) bqv[j] = bq[h * KS + j * 16 + m16];
      #pragma unroll
      for (int i = 0; i < 4; ++i) {
        us4 wp[4];
        #pragma unroll
        for (int r = 0; r < 4; ++r) {
          float v0 = acc[i][0][r] + bqv[0];
          float v1 = acc[i][1][r] + bqv[1];
          float v2 = acc[i][2][r] + bqv[2];
          float v3 = acc[i][3][r] + bqv[3];
          float mx = fmaxf(fmaxf(v0, v1), fmaxf(v2, v3));
          mx = fmaxf(mx, __shfl_xor(mx, 1));
          mx = fmaxf(mx, __shfl_xor(mx, 2));
          mx = fmaxf(mx, __shfl_xor(mx, 4));
          mx = fmaxf(mx, __shfl_xor(mx, 8));
          v0 = __expf(v0 - mx); v1 = __expf(v1 - mx);
          v2 = __expf(v2 - mx); v3 = __expf(v3 - mx);
          float s = v0 + v1 + v2 + v3;
          s += __shfl_xor(s, 1); s += __shfl_xor(s, 2);
          s += __shfl_xor(s, 4); s += __shfl_xor(s, 8);
          float inv = __builtin_amdgcn_rcpf(s);
          v0 *= inv; v1 *= inv; v2 *= inv; v3 *= inv;
          csum[0] += v0; csum[1] += v1; csum[2] += v2; csum[3] += v3;
          wp[0][r] = f2bf(v0); wp[1][r] = f2bf(v1);
          wp[2][r] = f2bf(v2); wp[3][r] = f2bf(v3);
        }
        #pragma unroll
        for (int j = 0; j < 4; ++j)
          *(us4*)(W_lds + (j * 16 + m16) * 136 + wm * 64 + i * 16 + q * 4) = wp[j];
      }
    } else {
      // these waves hold V: cols = head dims
      float bvv[4];
      #pragma unroll
      for (int j = 0; j < 4; ++j) bvv[j] = bv[h * HD + j * 16 + m16];
      #pragma unroll
      for (int i = 0; i < 4; ++i) {
        #pragma unroll
        for (int j = 0; j < 4; ++j) {
          us4 pk;
          pk.x = f2bf(acc[i][j][0] + bvv[j]);
          pk.y = f2bf(acc[i][j][1] + bvv[j]);
          pk.z = f2bf(acc[i][j][2] + bvv[j]);
          pk.w = f2bf(acc[i][j][3] + bvv[j]);
          *(us4*)(V_lds + (j * 16 + m16) * 136 + wm * 64 + i * 16 + q * 4) = pk;
        }
      }
    }
    __syncthreads();

    // phase 2: S_part[slot][d] += sum_tokens W[slot][t] * V[d][t]; each wave: 16 slots x 64 d
    #pragma unroll
    for (int kk = 0; kk < 4; ++kk) {
      bf16x8 a = *(const bf16x8*)(W_lds + (w * 16 + m16) * 136 + kk * 32 + q * 8);
      #pragma unroll
      for (int j = 0; j < 4; ++j) {
        bf16x8 bb = *(const bf16x8*)(V_lds + (j * 16 + m16) * 136 + kk * 32 + q * 8);
        acc2[j] = __builtin_amdgcn_mfma_f32_16x16x32_bf16(a, bb, acc2[j], 0, 0, 0);
      }
    }
  }

  // flush accumulators (one atomic pass for both chunks)
  float* Sb = Sacc + (size_t)bh * KS * HD;
  #pragma unroll
  for (int j = 0; j < 4; ++j)
    #pragma unroll
    for (int r = 0; r < 4; ++r)
      atomicAdd(Sb + (w * 16 + q * 4 + r) * HD + j * 16 + m16, acc2[j][r]);

  if (wn == 0) {
    #pragma unroll
    for (int j = 0; j < 4; ++j) {
      float c = csum[j];
      c += __shfl_xor(c, 16);
      c += __shfl_xor(c, 32);
      if (q == 0) atomicAdd(Cacc + (size_t)bh * KS + j * 16 + m16, c);
    }
  }
}

// ---------- finalize: divide by (C+eps), layernorm, write out ----------
__global__ void finalize_kernel(const float* __restrict__ Sacc, const float* __restrict__ Cacc,
                                const float* __restrict__ g, const float* __restrict__ bb,
                                float* __restrict__ out) {
  __shared__ float red[8];
  int bk_ = blockIdx.x;           // b*64 + k
  int b = bk_ >> 6, k = bk_ & 63;
  int tid = threadIdx.x;
  float v[2];
  #pragma unroll
  for (int m = 0; m < 2; ++m) {
    int d = tid + m*256;
    int h = d >> 6, dd = d & 63;
    float c = Cacc[((size_t)b*H + h)*KS + k];
    v[m] = Sacc[(((size_t)b*H + h)*KS + k)*HD + dd] / (c + EPS);
  }
  float s1 = v[0] + v[1], s2 = v[0]*v[0] + v[1]*v[1];
  for (int off = 32; off; off >>= 1) { s1 += __shfl_xor(s1, off); s2 += __shfl_xor(s2, off); }
  if ((tid & 63) == 0) { red[tid >> 6] = s1; red[4 + (tid >> 6)] = s2; }
  __syncthreads();
  s1 = red[0] + red[1] + red[2] + red[3];
  s2 = red[4] + red[5] + red[6] + red[7];
  float mu = s1 / D;
  float var = s2 / D - mu * mu;
  float rs = rsqrtf(var + LNEPS);
  #pragma unroll
  for (int m = 0; m < 2; ++m) {
    int d = tid + m*256;
    out[(size_t)bk_*D + d] = (v[m] - mu) * rs * g[d] + bb[d];
  }
}

extern "C" void kernel_launch(void* const* d_in, const int* in_sizes, int n_in,
                              void* d_out, int out_size, void* d_ws, size_t ws_size,
                              hipStream_t stream) {
  const float* X       = (const float*)d_in[0];
  const float* slots_w = (const float*)d_in[1];
  const float* g_slots = (const float*)d_in[2];
  const float* b_slots = (const float*)d_in[3];
  const float* Wk      = (const float*)d_in[4];
  const float* bk      = (const float*)d_in[5];
  const float* Wv      = (const float*)d_in[6];
  const float* bv      = (const float*)d_in[7];
  const float* g_after = (const float*)d_in[8];
  const float* b_after = (const float*)d_in[9];
  float* ws   = (float*)d_ws;
  float* S    = ws + OFF_S;
  float* bq   = ws + OFF_BQ;
  float* Sacc = ws + OFF_SACC;
  float* Cacc = ws + OFF_CACC;
  ushort_t* Wb2 = (ushort_t*)(ws + OFF_WB2);
  float* out  = (float*)d_out;

  hipLaunchKernelGGL(ln_slots_kernel, dim3(64), dim3(256), 0, stream, slots_w, g_slots, b_slots, S);
  hipLaunchKernelGGL(weff_kernel, dim3(1024), dim3(256), 0, stream, S, Wk, Wb2);
  hipLaunchKernelGGL(bq_kernel, dim3(2), dim3(256), 0, stream, S, bk, bq);
  hipLaunchKernelGGL(wvcopy_kernel, dim3(1024), dim3(256), 0, stream, Wv, Wb2);
  hipLaunchKernelGGL(zero_kernel, dim3(1040), dim3(256), 0, stream, Sacc, 266240);
  hipLaunchKernelGGL(main_kernel, dim3(2048), dim3(256), 0, stream, X, Wb2, bq, bv, Sacc, Cacc);
  hipLaunchKernelGGL(finalize_kernel, dim3(B * KS), dim3(256), 0, stream,
                     Sacc, Cacc, g_after, b_after, out);
}